// Round 9
// baseline (122.421 us; speedup 1.0000x reference)
//
#include <hip/hip_runtime.h>

#define NV    500000
#define ND    64
#define NH    4
#define NHID  256
#define NS    10000
#define NOUT  128
#define GSAMP 4                 // samples per block
#define FUSED_GRID (NS / GSAMP) // 2500

typedef __attribute__((ext_vector_type(8))) _Float16 f16x8;
typedef __attribute__((ext_vector_type(4))) _Float16 f16x4;
typedef __attribute__((ext_vector_type(4))) float    f32x4;

// ---------------------------------------------------------------------------
// Kernel W: write W_v as hi/lo f16 MFMA fragments in exact lane order.
// ---------------------------------------------------------------------------
__global__ __launch_bounds__(256) void wconv_kernel(
    const float* __restrict__ Wv, _Float16* __restrict__ WfH,
    _Float16* __restrict__ WfL)
{
    const int tid  = blockIdx.x * 256 + threadIdx.x;  // 0..2047
    const int lane = tid & 63;
    const int slot = tid >> 6;        // 0..31
    const int ks   = slot & 1;
    const int jt   = (slot >> 1) & 3;
    const int h    = slot >> 3;
    const int vcol = lane & 15;
    const int g    = lane >> 4;
    const int j    = h * 64 + jt * 16 + vcol;
    const int kb   = ks * 32 + g * 8;
    f16x8 hv, lv;
#pragma unroll
    for (int i = 0; i < 8; ++i) {
        const float w = Wv[(size_t)(kb + i) * NHID + j];
        const _Float16 hh = (_Float16)w;
        hv[i] = hh;
        lv[i] = (_Float16)(w - (float)hh);
    }
    *reinterpret_cast<f16x8*>(WfH + ((size_t)slot << 9) + (lane << 3)) = hv;
    *reinterpret_cast<f16x8*>(WfL + ((size_t)slot << 9) + (lane << 3)) = lv;
}

// ---------------------------------------------------------------------------
// Kernel B: segment boundaries from the SORTED map.
// ---------------------------------------------------------------------------
__global__ void bounds_kernel(const int* __restrict__ map, int* __restrict__ start)
{
    const int v = blockIdx.x * blockDim.x + threadIdx.x;
    if (v >= NV) return;
    const int cur = map[v];
    if (v == 0) {
        for (int s = 0; s <= cur; ++s) start[s] = 0;
    } else {
        const int prev = map[v - 1];
        for (int s = prev + 1; s <= cur; ++s) start[s] = v;
    }
    if (v == NV - 1) {
        for (int s = cur + 1; s <= NS; ++s) start[s] = NV;
    }
}

// ---------------------------------------------------------------------------
// Fused: scores (split-f16 MFMA) -> online softmax -> pooling; emb read once.
// vs R8 (single buffer, 2 barriers/chunk): T14 async-stage split. The NEXT
// chunk's 4 global loads are ISSUED right after the post-stage barrier and
// consumed (vmcnt; cvt; ds_write) at the top of the next iteration, so the
// ~500-900cy HBM latency hides under MFMA+softmax+pool. Next chunk start is
// always scalar: nc0 = (c0+64<en) ? c0+64 : en  (segments are contiguous).
// NO per-thread arrays / runtime-indexed state (R4/R5 spill lesson).
// ---------------------------------------------------------------------------
__global__ __launch_bounds__(256, 4) void fused_kernel(
    const float* __restrict__ emb,
    const _Float16* __restrict__ WfH, const _Float16* __restrict__ WfL,
    const int* __restrict__ start, float* __restrict__ pooled)
{
    __shared__ _Float16 EH[64 * 64];   // emb hi, swizzled rows (8 KB)
    __shared__ _Float16 EL[64 * 64];   // emb lo, swizzled rows (8 KB)
    __shared__ float    sbuf[NH][64];  // per-head chunk scores (1 KB)

    const int t    = threadIdx.x;
    const int lane = t & 63;
    const int h    = t >> 6;          // wave id == head
    const int vcol = lane & 15;       // MFMA col (v within 16-tile)
    const int g    = lane >> 4;       // k-group

    // ---- W fragments for head h: coalesced 16B/lane loads ----
    f16x8 wh[4][2], wl[4][2];
#pragma unroll
    for (int jt = 0; jt < 4; ++jt)
#pragma unroll
        for (int ks = 0; ks < 2; ++ks) {
            const int slot = ((h * 4 + jt) * 2 + ks);
            const size_t off = ((size_t)slot << 9) + (lane << 3);
            wh[jt][ks] = *reinterpret_cast<const f16x8*>(WfH + off);
            wl[jt][ks] = *reinterpret_cast<const f16x8*>(WfL + off);
        }

    const int s0   = blockIdx.x * GSAMP;
    const int bend = start[s0 + GSAMP];   // block's last row (exclusive)
    const int srow = t >> 4;              // 0..15 (stage row base within chunk)
    const int sk4  = (t & 15) << 2;       // k base: 0..60
    const int woff = (srow << 7) + ((sk4 << 1) ^ ((srow & 7) << 4)); // byte

    // in-flight prefetch registers (named; live across the compute phase)
    float4 x0, x1, x2, x3;
    int pf = -2;                          // chunk-start row the x-regs hold

    // prologue: prefetch the block's first chunk
    {
        const int st0 = start[s0];
        if (st0 < bend) {
            const int r0 = st0 + srow;
            if (r0      < NV) x0 = *reinterpret_cast<const float4*>(emb + (size_t)(r0     ) * ND + sk4);
            if (r0 + 16 < NV) x1 = *reinterpret_cast<const float4*>(emb + (size_t)(r0 + 16) * ND + sk4);
            if (r0 + 32 < NV) x2 = *reinterpret_cast<const float4*>(emb + (size_t)(r0 + 32) * ND + sk4);
            if (r0 + 48 < NV) x3 = *reinterpret_cast<const float4*>(emb + (size_t)(r0 + 48) * ND + sk4);
            pf = st0;
        }
    }

    for (int si = 0; si < GSAMP; ++si) {
        const int s  = s0 + si;
        const int st = start[s];
        const int en = start[s + 1];
        if (st >= en) { pooled[(size_t)s * NHID + t] = 0.f; continue; }

        float a0 = 0.f, a1 = 0.f, a2 = 0.f, a3 = 0.f;
        float m = -1e30f, l = 0.f;

        for (int c0 = st; c0 < en; c0 += 64) {
            const int C = min(64, en - c0);

            if (pf != c0) {   // cold path (should not happen; safety)
                const int r0 = c0 + srow;
                if (r0      < NV) x0 = *reinterpret_cast<const float4*>(emb + (size_t)(r0     ) * ND + sk4);
                if (r0 + 16 < NV) x1 = *reinterpret_cast<const float4*>(emb + (size_t)(r0 + 16) * ND + sk4);
                if (r0 + 32 < NV) x2 = *reinterpret_cast<const float4*>(emb + (size_t)(r0 + 32) * ND + sk4);
                if (r0 + 48 < NV) x3 = *reinterpret_cast<const float4*>(emb + (size_t)(r0 + 48) * ND + sk4);
            }

            // ---- stage from in-flight regs (zero-filled beyond C) ----
            {
                const float4 z = make_float4(0.f, 0.f, 0.f, 0.f);
                const float4 y0 = (srow      < C) ? x0 : z;
                const float4 y1 = (srow + 16 < C) ? x1 : z;
                const float4 y2 = (srow + 32 < C) ? x2 : z;
                const float4 y3 = (srow + 48 < C) ? x3 : z;
#define STAGE_ONE(Y, IT)                                                      \
                {                                                             \
                    f16x4 hv, lv;                                             \
                    const float xa[4] = {Y.x, Y.y, Y.z, Y.w};                 \
                    _Pragma("unroll")                                         \
                    for (int i = 0; i < 4; ++i) {                             \
                        const _Float16 hh = (_Float16)xa[i];                  \
                        hv[i] = hh;                                           \
                        lv[i] = (_Float16)(xa[i] - (float)hh);                \
                    }                                                         \
                    *reinterpret_cast<f16x4*>((char*)EH + woff + (IT << 11)) = hv; \
                    *reinterpret_cast<f16x4*>((char*)EL + woff + (IT << 11)) = lv; \
                }
                STAGE_ONE(y0, 0)
                STAGE_ONE(y1, 1)
                STAGE_ONE(y2, 2)
                STAGE_ONE(y3, 3)
#undef STAGE_ONE
            }
            __syncthreads();   // stage visible to all waves

            // ---- T14: issue NEXT chunk's loads now; consume next iteration --
            {
                const int nc0 = (c0 + 64 < en) ? (c0 + 64) : en;
                if (nc0 < bend) {
                    const int r0 = nc0 + srow;
                    if (r0      < NV) x0 = *reinterpret_cast<const float4*>(emb + (size_t)(r0     ) * ND + sk4);
                    if (r0 + 16 < NV) x1 = *reinterpret_cast<const float4*>(emb + (size_t)(r0 + 16) * ND + sk4);
                    if (r0 + 32 < NV) x2 = *reinterpret_cast<const float4*>(emb + (size_t)(r0 + 32) * ND + sk4);
                    if (r0 + 48 < NV) x3 = *reinterpret_cast<const float4*>(emb + (size_t)(r0 + 48) * ND + sk4);
                    pf = nc0;
                } else {
                    pf = -2;
                }
            }

            // ---- scores for head h over the chunk ----
            const int nvt = (C + 15) >> 4;
            for (int vt = 0; vt < nvt; ++vt) {
                const int row = (vt << 4) + vcol;
                const int rb  = row << 7;
                const int sw  = (row & 7) << 4;
                const f16x8 bh0 = *reinterpret_cast<const f16x8*>(
                    (const char*)EH + rb + (((g << 4)) ^ sw));
                const f16x8 bh1 = *reinterpret_cast<const f16x8*>(
                    (const char*)EH + rb + ((64 | (g << 4)) ^ sw));
                const f16x8 bl0 = *reinterpret_cast<const f16x8*>(
                    (const char*)EL + rb + (((g << 4)) ^ sw));
                const f16x8 bl1 = *reinterpret_cast<const f16x8*>(
                    (const char*)EL + rb + ((64 | (g << 4)) ^ sw));
                float sreg = 0.f;
#pragma unroll
                for (int jt = 0; jt < 4; ++jt) {
                    f32x4 a4 = {0.f, 0.f, 0.f, 0.f};
                    a4 = __builtin_amdgcn_mfma_f32_16x16x32_f16(wh[jt][0], bh0, a4, 0, 0, 0);
                    a4 = __builtin_amdgcn_mfma_f32_16x16x32_f16(wh[jt][1], bh1, a4, 0, 0, 0);
                    a4 = __builtin_amdgcn_mfma_f32_16x16x32_f16(wh[jt][0], bl0, a4, 0, 0, 0);
                    a4 = __builtin_amdgcn_mfma_f32_16x16x32_f16(wh[jt][1], bl1, a4, 0, 0, 0);
                    a4 = __builtin_amdgcn_mfma_f32_16x16x32_f16(wl[jt][0], bh0, a4, 0, 0, 0);
                    a4 = __builtin_amdgcn_mfma_f32_16x16x32_f16(wl[jt][1], bh1, a4, 0, 0, 0);
                    sreg += a4[0]*a4[0] + a4[1]*a4[1] + a4[2]*a4[2] + a4[3]*a4[3];
                }
                sreg += __shfl_xor(sreg, 16, 64);
                sreg += __shfl_xor(sreg, 32, 64);
                if (lane < 16) sbuf[h][(vt << 4) + lane] = sreg;
            }

            // ---- online softmax update (wave-local) ----
            const float sc = (lane < C) ? sbuf[h][lane] : -1e30f;
            float cmax = sc;
#pragma unroll
            for (int off = 1; off < 64; off <<= 1)
                cmax = fmaxf(cmax, __shfl_xor(cmax, off, 64));
            const float mn = fmaxf(m, cmax);
            const float r  = __expf(m - mn);
            const float e  = (lane < C) ? __expf(sc - mn) : 0.f;
            float csum = e;
#pragma unroll
            for (int off = 1; off < 64; off <<= 1)
                csum += __shfl_xor(csum, off, 64);
            l = l * r + csum;
            m = mn;
            a0 *= r; a1 *= r; a2 *= r; a3 *= r;

            // ---- pooling: e via readlane (VALU), emb via hi-f16 u16 reads ---
            const unsigned eb = __float_as_uint(e);
            const int qmax = (C + 3) >> 2;      // uniform
#pragma unroll
            for (int q = 0; q < 16; ++q) {
                if (q < qmax) {
                    const float e0 = __uint_as_float(__builtin_amdgcn_readlane(eb, 4*q + 0));
                    const float e1 = __uint_as_float(__builtin_amdgcn_readlane(eb, 4*q + 1));
                    const float e2 = __uint_as_float(__builtin_amdgcn_readlane(eb, 4*q + 2));
                    const float e3 = __uint_as_float(__builtin_amdgcn_readlane(eb, 4*q + 3));
                    const int v0 = 4*q;
                    const float f0 = (float)*reinterpret_cast<const _Float16*>(
                        (const char*)EH + ((v0 + 0) << 7) + ((lane << 1) ^ (((v0 + 0) & 7) << 4)));
                    const float f1 = (float)*reinterpret_cast<const _Float16*>(
                        (const char*)EH + ((v0 + 1) << 7) + ((lane << 1) ^ (((v0 + 1) & 7) << 4)));
                    const float f2 = (float)*reinterpret_cast<const _Float16*>(
                        (const char*)EH + ((v0 + 2) << 7) + ((lane << 1) ^ (((v0 + 2) & 7) << 4)));
                    const float f3 = (float)*reinterpret_cast<const _Float16*>(
                        (const char*)EH + ((v0 + 3) << 7) + ((lane << 1) ^ (((v0 + 3) & 7) << 4)));
                    a0 = fmaf(e0, f0, a0);
                    a1 = fmaf(e1, f1, a1);
                    a2 = fmaf(e2, f2, a2);
                    a3 = fmaf(e3, f3, a3);
                }
            }
            __syncthreads();   // all waves done reading before next stage
        }
        pooled[(size_t)s * NHID + t] = ((a0 + a1) + (a2 + a3)) / l;
    }
}

// ---------------------------------------------------------------------------
// Kernel D: out = pooled @ W_out
// ---------------------------------------------------------------------------
__global__ __launch_bounds__(256) void out_kernel(
    const float* __restrict__ pooled, const float* __restrict__ Wout,
    float* __restrict__ out)
{
    __shared__ float Pt[16][260];
    const int t = threadIdx.x;
    const int sbase = blockIdx.x << 4;
#pragma unroll
    for (int it = 0; it < 4; ++it) {
        const int idx = t + (it << 8);
        const int row = idx >> 6;
        const int c4 = (idx & 63) << 2;
        *reinterpret_cast<float4*>(&Pt[row][c4]) =
            *reinterpret_cast<const float4*>(pooled + (size_t)(sbase + row) * NHID + c4);
    }
    __syncthreads();
    const int oc = (t & 31) << 2;
    const int sg = t >> 5;
    float a0x = 0.f, a0y = 0.f, a0z = 0.f, a0w = 0.f;
    float a1x = 0.f, a1y = 0.f, a1z = 0.f, a1w = 0.f;
#pragma unroll 4
    for (int k = 0; k < NHID; ++k) {
        const float4 w = *reinterpret_cast<const float4*>(Wout + (size_t)k * NOUT + oc);
        const float p0 = Pt[(sg << 1) + 0][k];
        const float p1 = Pt[(sg << 1) + 1][k];
        a0x = fmaf(p0, w.x, a0x); a0y = fmaf(p0, w.y, a0y);
        a0z = fmaf(p0, w.z, a0z); a0w = fmaf(p0, w.w, a0w);
        a1x = fmaf(p1, w.x, a1x); a1y = fmaf(p1, w.y, a1y);
        a1z = fmaf(p1, w.z, a1z); a1w = fmaf(p1, w.w, a1w);
    }
    *reinterpret_cast<float4*>(out + (size_t)(sbase + (sg << 1) + 0) * NOUT + oc) =
        make_float4(a0x, a0y, a0z, a0w);
    *reinterpret_cast<float4*>(out + (size_t)(sbase + (sg << 1) + 1) * NOUT + oc) =
        make_float4(a1x, a1y, a1z, a1w);
}

// ---------------------------------------------------------------------------
extern "C" void kernel_launch(void* const* d_in, const int* in_sizes, int n_in,
                              void* d_out, int out_size, void* d_ws, size_t ws_size,
                              hipStream_t stream)
{
    const float* emb  = (const float*)d_in[0];
    const float* Wv   = (const float*)d_in[1];
    const float* Wout = (const float*)d_in[2];
    const int*   map  = (const int*)d_in[3];
    float* out = (float*)d_out;

    char* ws = (char*)d_ws;
    float*    pooled = (float*)ws;                    // 10,240,000 B
    int*      start  = (int*)(ws + 10240000);         //     40,004 B
    _Float16* WfH    = (_Float16*)(ws + 10280064);    //     32,768 B
    _Float16* WfL    = (_Float16*)(ws + 10312832);    //     32,768 B

    wconv_kernel<<<8, 256, 0, stream>>>(Wv, WfH, WfL);
    bounds_kernel<<<(NV + 255) / 256, 256, 0, stream>>>(map, start);
    fused_kernel<<<FUSED_GRID, 256, 0, stream>>>(emb, WfH, WfL, start, pooled);
    out_kernel<<<NS / 16, 256, 0, stream>>>(pooled, Wout, out);
}

// Round 10
// 118.276 us; speedup vs baseline: 1.0350x; 1.0350x over previous
//
#include <hip/hip_runtime.h>

#define NV    500000
#define ND    64
#define NH    4
#define NHID  256
#define NS    10000
#define NOUT  128
#define BROWS 256                         // nominal rows per block
#define NBLK  ((NV + BROWS - 1) / BROWS)  // 1954

typedef __attribute__((ext_vector_type(8))) _Float16 f16x8;
typedef __attribute__((ext_vector_type(4))) _Float16 f16x4;
typedef __attribute__((ext_vector_type(4))) float    f32x4;

// ---------------------------------------------------------------------------
// Kernel W: write W_v as hi/lo f16 MFMA fragments in exact lane order.
// ---------------------------------------------------------------------------
__global__ __launch_bounds__(256) void wconv_kernel(
    const float* __restrict__ Wv, _Float16* __restrict__ WfH,
    _Float16* __restrict__ WfL)
{
    const int tid  = blockIdx.x * 256 + threadIdx.x;  // 0..2047
    const int lane = tid & 63;
    const int slot = tid >> 6;        // 0..31
    const int ks   = slot & 1;
    const int jt   = (slot >> 1) & 3;
    const int h    = slot >> 3;
    const int vcol = lane & 15;
    const int g    = lane >> 4;
    const int j    = h * 64 + jt * 16 + vcol;
    const int kb   = ks * 32 + g * 8;
    f16x8 hv, lv;
#pragma unroll
    for (int i = 0; i < 8; ++i) {
        const float w = Wv[(size_t)(kb + i) * NHID + j];
        const _Float16 hh = (_Float16)w;
        hv[i] = hh;
        lv[i] = (_Float16)(w - (float)hh);
    }
    *reinterpret_cast<f16x8*>(WfH + ((size_t)slot << 9) + (lane << 3)) = hv;
    *reinterpret_cast<f16x8*>(WfL + ((size_t)slot << 9) + (lane << 3)) = lv;
}

// ---------------------------------------------------------------------------
// Kernel B: segment boundaries from the SORTED map.
// ---------------------------------------------------------------------------
__global__ void bounds_kernel(const int* __restrict__ map, int* __restrict__ start)
{
    const int v = blockIdx.x * blockDim.x + threadIdx.x;
    if (v >= NV) return;
    const int cur = map[v];
    if (v == 0) {
        for (int s = 0; s <= cur; ++s) start[s] = 0;
    } else {
        const int prev = map[v - 1];
        for (int s = prev + 1; s <= cur; ++s) start[s] = v;
    }
    if (v == NV - 1) {
        for (int s = cur + 1; s <= NS; ++s) start[s] = NV;
    }
}

// ---------------------------------------------------------------------------
// Kernel S: sfirst[b] = first sample s with start[s] >= b*BROWS (binary search)
// ---------------------------------------------------------------------------
__global__ void sfirst_kernel(const int* __restrict__ start, int* __restrict__ sf)
{
    const int b = blockIdx.x * blockDim.x + threadIdx.x;
    if (b > NBLK) return;
    const int target = b * BROWS;
    int lo = 0, hi = NS;
    while (lo < hi) {
        const int mid = (lo + hi) >> 1;
        if (start[mid] >= target) hi = mid; else lo = mid + 1;
    }
    sf[b] = lo;
}

// ---------------------------------------------------------------------------
// Fused: dense 64-row chunks over block-owned sample ranges.
// Block b owns samples [sf[b], sf[b+1]); rows [start[sf[b]], start[sf[b+1]]).
// Chunks span sample boundaries; per-chunk sub-segment loop does masked
// online-softmax + windowed pooling; finalize when a sample ends in-chunk.
// Per-chunk machinery (stage/MFMA/pool) identical to R8.
// ---------------------------------------------------------------------------
__global__ __launch_bounds__(256, 4) void fused_kernel(
    const float* __restrict__ emb,
    const _Float16* __restrict__ WfH, const _Float16* __restrict__ WfL,
    const int* __restrict__ start, const int* __restrict__ sf,
    float* __restrict__ pooled)
{
    __shared__ _Float16 EH[64 * 64];   // emb hi, swizzled rows (8 KB)
    __shared__ _Float16 EL[64 * 64];   // emb lo, swizzled rows (8 KB)
    __shared__ float    sbuf[NH][64];  // per-head chunk scores (1 KB)

    const int t    = threadIdx.x;
    const int lane = t & 63;
    const int h    = t >> 6;          // wave id == head
    const int vcol = lane & 15;       // MFMA col (v within 16-tile)
    const int g    = lane >> 4;       // k-group

    // ---- W fragments for head h: coalesced 16B/lane loads ----
    f16x8 wh[4][2], wl[4][2];
#pragma unroll
    for (int jt = 0; jt < 4; ++jt)
#pragma unroll
        for (int ks = 0; ks < 2; ++ks) {
            const int slot = ((h * 4 + jt) * 2 + ks);
            const size_t off = ((size_t)slot << 9) + (lane << 3);
            wh[jt][ks] = *reinterpret_cast<const f16x8*>(WfH + off);
            wl[jt][ks] = *reinterpret_cast<const f16x8*>(WfL + off);
        }

    const int b    = blockIdx.x;
    int       s    = sf[b];
    const int send = sf[b + 1];
    if (s >= send) return;
    const int r_lo = start[s];
    const int r_hi = start[send];

    int st_s = r_lo;                  // current sample bounds
    int en_s = start[s + 1];

    const int srow = t >> 4;          // 0..15 (stage row base within chunk)
    const int sk4  = (t & 15) << 2;   // k base: 0..60
    const int woff = (srow << 7) + ((sk4 << 1) ^ ((srow & 7) << 4)); // byte

    float a0 = 0.f, a1 = 0.f, a2 = 0.f, a3 = 0.f;  // pool accums (h, d=lane)
    float m = -1e30f, l = 0.f;                      // running softmax state

    for (int c0 = r_lo; c0 < r_hi && s < send; c0 += 64) {
        const int C = min(64, r_hi - c0);

        // ---- stage chunk (zero-filled beyond C) ----
#pragma unroll
        for (int it = 0; it < 4; ++it) {
            const int row = srow + (it << 4);
            float4 x = make_float4(0.f, 0.f, 0.f, 0.f);
            if (row < C)
                x = *reinterpret_cast<const float4*>(
                    emb + (size_t)(c0 + row) * ND + sk4);
            f16x4 hv, lv;
            const float xa[4] = {x.x, x.y, x.z, x.w};
#pragma unroll
            for (int i = 0; i < 4; ++i) {
                const _Float16 hh = (_Float16)xa[i];
                hv[i] = hh;
                lv[i] = (_Float16)(xa[i] - (float)hh);
            }
            *reinterpret_cast<f16x4*>((char*)EH + woff + (it << 11)) = hv;
            *reinterpret_cast<f16x4*>((char*)EL + woff + (it << 11)) = lv;
        }
        __syncthreads();   // stage visible to all waves

        // ---- scores for head h over the whole chunk ----
#pragma unroll
        for (int vt = 0; vt < 4; ++vt) {
            const int row = (vt << 4) + vcol;
            const int rb  = row << 7;
            const int sw  = (row & 7) << 4;
            const f16x8 bh0 = *reinterpret_cast<const f16x8*>(
                (const char*)EH + rb + (((g << 4)) ^ sw));
            const f16x8 bh1 = *reinterpret_cast<const f16x8*>(
                (const char*)EH + rb + ((64 | (g << 4)) ^ sw));
            const f16x8 bl0 = *reinterpret_cast<const f16x8*>(
                (const char*)EL + rb + (((g << 4)) ^ sw));
            const f16x8 bl1 = *reinterpret_cast<const f16x8*>(
                (const char*)EL + rb + ((64 | (g << 4)) ^ sw));
            float sreg = 0.f;
#pragma unroll
            for (int jt = 0; jt < 4; ++jt) {
                f32x4 a4 = {0.f, 0.f, 0.f, 0.f};
                a4 = __builtin_amdgcn_mfma_f32_16x16x32_f16(wh[jt][0], bh0, a4, 0, 0, 0);
                a4 = __builtin_amdgcn_mfma_f32_16x16x32_f16(wh[jt][1], bh1, a4, 0, 0, 0);
                a4 = __builtin_amdgcn_mfma_f32_16x16x32_f16(wh[jt][0], bl0, a4, 0, 0, 0);
                a4 = __builtin_amdgcn_mfma_f32_16x16x32_f16(wh[jt][1], bl1, a4, 0, 0, 0);
                a4 = __builtin_amdgcn_mfma_f32_16x16x32_f16(wl[jt][0], bh0, a4, 0, 0, 0);
                a4 = __builtin_amdgcn_mfma_f32_16x16x32_f16(wl[jt][1], bh1, a4, 0, 0, 0);
                sreg += a4[0]*a4[0] + a4[1]*a4[1] + a4[2]*a4[2] + a4[3]*a4[3];
            }
            sreg += __shfl_xor(sreg, 16, 64);
            sreg += __shfl_xor(sreg, 32, 64);
            if (lane < 16) sbuf[h][(vt << 4) + lane] = sreg;
        }
        const float sc = sbuf[h][lane];   // same wave wrote it

        // ---- sub-segment loop: masked online softmax + windowed pool ----
        while (s < send && st_s < c0 + 64) {
            const int lo = max(st_s - c0, 0);
            const int hi = min(en_s - c0, 64);
            if (hi > lo) {
                const bool inwin = (lane >= lo) && (lane < hi);
                const float scm = inwin ? sc : -1e30f;
                float cmax = scm;
#pragma unroll
                for (int off = 1; off < 64; off <<= 1)
                    cmax = fmaxf(cmax, __shfl_xor(cmax, off, 64));
                const float mn = fmaxf(m, cmax);
                const float r  = __expf(m - mn);
                const float e  = inwin ? __expf(sc - mn) : 0.f;
                float csum = e;
#pragma unroll
                for (int off = 1; off < 64; off <<= 1)
                    csum += __shfl_xor(csum, off, 64);
                l = l * r + csum;
                m = mn;
                a0 *= r; a1 *= r; a2 *= r; a3 *= r;

                // pool over the window's q-range (e=0 outside window)
                const unsigned eb = __float_as_uint(e);
                const int q_lo = lo >> 2;
                const int q_hi = (hi + 3) >> 2;
                for (int q = q_lo; q < q_hi; ++q) {
                    const int v0 = q << 2;
                    const float e0 = __uint_as_float(__builtin_amdgcn_readlane(eb, v0 + 0));
                    const float e1 = __uint_as_float(__builtin_amdgcn_readlane(eb, v0 + 1));
                    const float e2 = __uint_as_float(__builtin_amdgcn_readlane(eb, v0 + 2));
                    const float e3 = __uint_as_float(__builtin_amdgcn_readlane(eb, v0 + 3));
                    const float f0 = (float)*reinterpret_cast<const _Float16*>(
                        (const char*)EH + ((v0 + 0) << 7) + ((lane << 1) ^ (((v0 + 0) & 7) << 4)));
                    const float f1 = (float)*reinterpret_cast<const _Float16*>(
                        (const char*)EH + ((v0 + 1) << 7) + ((lane << 1) ^ (((v0 + 1) & 7) << 4)));
                    const float f2 = (float)*reinterpret_cast<const _Float16*>(
                        (const char*)EH + ((v0 + 2) << 7) + ((lane << 1) ^ (((v0 + 2) & 7) << 4)));
                    const float f3 = (float)*reinterpret_cast<const _Float16*>(
                        (const char*)EH + ((v0 + 3) << 7) + ((lane << 1) ^ (((v0 + 3) & 7) << 4)));
                    a0 = fmaf(e0, f0, a0);
                    a1 = fmaf(e1, f1, a1);
                    a2 = fmaf(e2, f2, a2);
                    a3 = fmaf(e3, f3, a3);
                }
            }
            if (en_s <= c0 + 64) {
                // sample s ends in this chunk: finalize
                const float sum = (a0 + a1) + (a2 + a3);
                pooled[(size_t)s * NHID + t] = (l > 0.f) ? sum / l : 0.f;
                a0 = a1 = a2 = a3 = 0.f; m = -1e30f; l = 0.f;
                ++s;
                if (s < send) { st_s = en_s; en_s = start[s + 1]; }
            } else {
                break;   // sample continues into next chunk
            }
        }
        __syncthreads();   // all waves done reading EH before next stage
    }
    // degenerate: trailing empty samples in a zero-row block
    while (s < send) {
        pooled[(size_t)s * NHID + t] = 0.f;
        ++s;
    }
}

// ---------------------------------------------------------------------------
// Kernel D: out = pooled @ W_out
// ---------------------------------------------------------------------------
__global__ __launch_bounds__(256) void out_kernel(
    const float* __restrict__ pooled, const float* __restrict__ Wout,
    float* __restrict__ out)
{
    __shared__ float Pt[16][260];
    const int t = threadIdx.x;
    const int sbase = blockIdx.x << 4;
#pragma unroll
    for (int it = 0; it < 4; ++it) {
        const int idx = t + (it << 8);
        const int row = idx >> 6;
        const int c4 = (idx & 63) << 2;
        *reinterpret_cast<float4*>(&Pt[row][c4]) =
            *reinterpret_cast<const float4*>(pooled + (size_t)(sbase + row) * NHID + c4);
    }
    __syncthreads();
    const int oc = (t & 31) << 2;
    const int sg = t >> 5;
    float a0x = 0.f, a0y = 0.f, a0z = 0.f, a0w = 0.f;
    float a1x = 0.f, a1y = 0.f, a1z = 0.f, a1w = 0.f;
#pragma unroll 4
    for (int k = 0; k < NHID; ++k) {
        const float4 w = *reinterpret_cast<const float4*>(Wout + (size_t)k * NOUT + oc);
        const float p0 = Pt[(sg << 1) + 0][k];
        const float p1 = Pt[(sg << 1) + 1][k];
        a0x = fmaf(p0, w.x, a0x); a0y = fmaf(p0, w.y, a0y);
        a0z = fmaf(p0, w.z, a0z); a0w = fmaf(p0, w.w, a0w);
        a1x = fmaf(p1, w.x, a1x); a1y = fmaf(p1, w.y, a1y);
        a1z = fmaf(p1, w.z, a1z); a1w = fmaf(p1, w.w, a1w);
    }
    *reinterpret_cast<float4*>(out + (size_t)(sbase + (sg << 1) + 0) * NOUT + oc) =
        make_float4(a0x, a0y, a0z, a0w);
    *reinterpret_cast<float4*>(out + (size_t)(sbase + (sg << 1) + 1) * NOUT + oc) =
        make_float4(a1x, a1y, a1z, a1w);
}

// ---------------------------------------------------------------------------
extern "C" void kernel_launch(void* const* d_in, const int* in_sizes, int n_in,
                              void* d_out, int out_size, void* d_ws, size_t ws_size,
                              hipStream_t stream)
{
    const float* emb  = (const float*)d_in[0];
    const float* Wv   = (const float*)d_in[1];
    const float* Wout = (const float*)d_in[2];
    const int*   map  = (const int*)d_in[3];
    float* out = (float*)d_out;

    char* ws = (char*)d_ws;
    float*    pooled = (float*)ws;                    // 10,240,000 B
    int*      start  = (int*)(ws + 10240000);         //     40,004 B
    _Float16* WfH    = (_Float16*)(ws + 10280064);    //     32,768 B
    _Float16* WfL    = (_Float16*)(ws + 10312832);    //     32,768 B
    int*      sf     = (int*)(ws + 10345600);         //      7,820 B

    wconv_kernel<<<8, 256, 0, stream>>>(Wv, WfH, WfL);
    bounds_kernel<<<(NV + 255) / 256, 256, 0, stream>>>(map, start);
    sfirst_kernel<<<(NBLK + 256) / 256, 256, 0, stream>>>(start, sf);
    fused_kernel<<<NBLK, 256, 0, stream>>>(emb, WfH, WfL, start, sf, pooled);
    out_kernel<<<NS / 16, 256, 0, stream>>>(pooled, Wout, out);
}

// Round 12
// 101.990 us; speedup vs baseline: 1.2003x; 1.1597x over previous
//
#include <hip/hip_runtime.h>

#define NV    500000
#define ND    64
#define NH    4
#define NHID  256
#define NS    10000
#define NOUT  128
#define GSAMP 2                 // samples per block
#define FUSED_GRID (NS / GSAMP) // 5000

typedef __attribute__((ext_vector_type(8))) _Float16 f16x8;
typedef __attribute__((ext_vector_type(4))) _Float16 f16x4;
typedef __attribute__((ext_vector_type(2))) __fp16   hf16x2;   // cvt_pkrtz result type
typedef __attribute__((ext_vector_type(4))) float    f32x4;

// ---------------------------------------------------------------------------
// Kernel W: write W_v as hi/lo f16 MFMA fragments in exact lane order.
// ---------------------------------------------------------------------------
__global__ __launch_bounds__(256) void wconv_kernel(
    const float* __restrict__ Wv, _Float16* __restrict__ WfH,
    _Float16* __restrict__ WfL)
{
    const int tid  = blockIdx.x * 256 + threadIdx.x;  // 0..2047
    const int lane = tid & 63;
    const int slot = tid >> 6;        // 0..31
    const int ks   = slot & 1;
    const int jt   = (slot >> 1) & 3;
    const int h    = slot >> 3;
    const int vcol = lane & 15;
    const int g    = lane >> 4;
    const int j    = h * 64 + jt * 16 + vcol;
    const int kb   = ks * 32 + g * 8;
    f16x8 hv, lv;
#pragma unroll
    for (int i = 0; i < 8; ++i) {
        const float w = Wv[(size_t)(kb + i) * NHID + j];
        const _Float16 hh = (_Float16)w;
        hv[i] = hh;
        lv[i] = (_Float16)(w - (float)hh);
    }
    *reinterpret_cast<f16x8*>(WfH + ((size_t)slot << 9) + (lane << 3)) = hv;
    *reinterpret_cast<f16x8*>(WfL + ((size_t)slot << 9) + (lane << 3)) = lv;
}

// ---------------------------------------------------------------------------
// Kernel B: segment boundaries from the SORTED map.
// ---------------------------------------------------------------------------
__global__ void bounds_kernel(const int* __restrict__ map, int* __restrict__ start)
{
    const int v = blockIdx.x * blockDim.x + threadIdx.x;
    if (v >= NV) return;
    const int cur = map[v];
    if (v == 0) {
        for (int s = 0; s <= cur; ++s) start[s] = 0;
    } else {
        const int prev = map[v - 1];
        for (int s = prev + 1; s <= cur; ++s) start[s] = v;
    }
    if (v == NV - 1) {
        for (int s = cur + 1; s <= NS; ++s) start[s] = NV;
    }
}

// ---------------------------------------------------------------------------
// Fused: scores (split-f16 MFMA) -> online softmax -> pooling; emb read once.
// vs R8: (1) sbuf LDS round-trip replaced by static cndmask select of the 4
// per-vt scores; (2) cvt_pkrtz packed f32->f16 staging; (3) s_setprio around
// the MFMA cluster; (4) GSAMP=2 (5000 blocks, better balance).
// ---------------------------------------------------------------------------
__global__ __launch_bounds__(256, 4) void fused_kernel(
    const float* __restrict__ emb,
    const _Float16* __restrict__ WfH, const _Float16* __restrict__ WfL,
    const int* __restrict__ start, float* __restrict__ pooled)
{
    __shared__ _Float16 EH[64 * 64];   // emb hi, swizzled rows (8 KB)
    __shared__ _Float16 EL[64 * 64];   // emb lo, swizzled rows (8 KB)

    const int t    = threadIdx.x;
    const int lane = t & 63;
    const int h    = t >> 6;          // wave id == head
    const int vcol = lane & 15;       // MFMA col (v within 16-tile)
    const int g    = lane >> 4;       // k-group

    // ---- W fragments for head h: coalesced 16B/lane loads ----
    f16x8 wh[4][2], wl[4][2];
#pragma unroll
    for (int jt = 0; jt < 4; ++jt)
#pragma unroll
        for (int ks = 0; ks < 2; ++ks) {
            const int slot = ((h * 4 + jt) * 2 + ks);
            const size_t off = ((size_t)slot << 9) + (lane << 3);
            wh[jt][ks] = *reinterpret_cast<const f16x8*>(WfH + off);
            wl[jt][ks] = *reinterpret_cast<const f16x8*>(WfL + off);
        }

    const int s0 = blockIdx.x * GSAMP;
    const int srow = t >> 4;          // 0..15 (stage row base within chunk)
    const int sk4  = (t & 15) << 2;   // k base: 0..60
    const int woff = (srow << 7) + ((sk4 << 1) ^ ((srow & 7) << 4)); // byte

    for (int si = 0; si < GSAMP; ++si) {
        const int s  = s0 + si;
        const int st = start[s];
        const int en = start[s + 1];
        if (st >= en) { pooled[(size_t)s * NHID + t] = 0.f; continue; }

        float a0 = 0.f, a1 = 0.f, a2 = 0.f, a3 = 0.f;
        float m = -1e30f, l = 0.f;

        for (int c0 = st; c0 < en; c0 += 64) {
            const int C = min(64, en - c0);

            // ---- stage chunk (zero-filled beyond C), packed cvt ----
#pragma unroll
            for (int it = 0; it < 4; ++it) {
                const int row = srow + (it << 4);
                float4 x = make_float4(0.f, 0.f, 0.f, 0.f);
                if (row < C)
                    x = *reinterpret_cast<const float4*>(
                        emb + (size_t)(c0 + row) * ND + sk4);
                const hf16x2 h01 = __builtin_amdgcn_cvt_pkrtz(x.x, x.y);
                const hf16x2 h23 = __builtin_amdgcn_cvt_pkrtz(x.z, x.w);
                const float l0 = x.x - (float)h01[0];
                const float l1 = x.y - (float)h01[1];
                const float l2 = x.z - (float)h23[0];
                const float l3 = x.w - (float)h23[1];
                const hf16x2 q01 = __builtin_amdgcn_cvt_pkrtz(l0, l1);
                const hf16x2 q23 = __builtin_amdgcn_cvt_pkrtz(l2, l3);
                f16x4 hv, lv;
                hv[0] = (_Float16)h01[0]; hv[1] = (_Float16)h01[1];
                hv[2] = (_Float16)h23[0]; hv[3] = (_Float16)h23[1];
                lv[0] = (_Float16)q01[0]; lv[1] = (_Float16)q01[1];
                lv[2] = (_Float16)q23[0]; lv[3] = (_Float16)q23[1];
                *reinterpret_cast<f16x4*>((char*)EH + woff + (it << 11)) = hv;
                *reinterpret_cast<f16x4*>((char*)EL + woff + (it << 11)) = lv;
            }
            __syncthreads();   // stage visible to all waves

            // ---- scores for head h over the chunk (setprio around MFMA) ----
            float sv[4];       // statically indexed (full unroll)
            __builtin_amdgcn_s_setprio(1);
#pragma unroll
            for (int vt = 0; vt < 4; ++vt) {
                const int row = (vt << 4) + vcol;
                const int rb  = row << 7;
                const int sw  = (row & 7) << 4;
                const f16x8 bh0 = *reinterpret_cast<const f16x8*>(
                    (const char*)EH + rb + (((g << 4)) ^ sw));
                const f16x8 bh1 = *reinterpret_cast<const f16x8*>(
                    (const char*)EH + rb + ((64 | (g << 4)) ^ sw));
                const f16x8 bl0 = *reinterpret_cast<const f16x8*>(
                    (const char*)EL + rb + (((g << 4)) ^ sw));
                const f16x8 bl1 = *reinterpret_cast<const f16x8*>(
                    (const char*)EL + rb + ((64 | (g << 4)) ^ sw));
                float sreg = 0.f;
#pragma unroll
                for (int jt = 0; jt < 4; ++jt) {
                    f32x4 a4 = {0.f, 0.f, 0.f, 0.f};
                    a4 = __builtin_amdgcn_mfma_f32_16x16x32_f16(wh[jt][0], bh0, a4, 0, 0, 0);
                    a4 = __builtin_amdgcn_mfma_f32_16x16x32_f16(wh[jt][1], bh1, a4, 0, 0, 0);
                    a4 = __builtin_amdgcn_mfma_f32_16x16x32_f16(wh[jt][0], bl0, a4, 0, 0, 0);
                    a4 = __builtin_amdgcn_mfma_f32_16x16x32_f16(wh[jt][1], bl1, a4, 0, 0, 0);
                    a4 = __builtin_amdgcn_mfma_f32_16x16x32_f16(wl[jt][0], bh0, a4, 0, 0, 0);
                    a4 = __builtin_amdgcn_mfma_f32_16x16x32_f16(wl[jt][1], bh1, a4, 0, 0, 0);
                    sreg += a4[0]*a4[0] + a4[1]*a4[1] + a4[2]*a4[2] + a4[3]*a4[3];
                }
                sreg += __shfl_xor(sreg, 16, 64);
                sreg += __shfl_xor(sreg, 32, 64);
                sv[vt] = sreg;     // lane holds score for v = vt*16 + (lane&15)
            }
            __builtin_amdgcn_s_setprio(0);

            // lane's own score (v = lane): static cndmask select, no LDS
            const float scA = (lane & 16) ? sv[1] : sv[0];
            const float scB = (lane & 16) ? sv[3] : sv[2];
            const float scO = (lane & 32) ? scB : scA;

            // ---- online softmax update (wave-local) ----
            const float sc = (lane < C) ? scO : -1e30f;
            float cmax = sc;
#pragma unroll
            for (int off = 1; off < 64; off <<= 1)
                cmax = fmaxf(cmax, __shfl_xor(cmax, off, 64));
            const float mn = fmaxf(m, cmax);
            const float r  = __expf(m - mn);
            const float e  = (lane < C) ? __expf(sc - mn) : 0.f;
            float csum = e;
#pragma unroll
            for (int off = 1; off < 64; off <<= 1)
                csum += __shfl_xor(csum, off, 64);
            l = l * r + csum;
            m = mn;
            a0 *= r; a1 *= r; a2 *= r; a3 *= r;

            // ---- pooling: e via readlane (VALU), emb via hi-f16 u16 reads ---
            const unsigned eb = __float_as_uint(e);
            const int qmax = (C + 3) >> 2;      // uniform
#pragma unroll
            for (int q = 0; q < 16; ++q) {
                if (q < qmax) {
                    const float e0 = __uint_as_float(__builtin_amdgcn_readlane(eb, 4*q + 0));
                    const float e1 = __uint_as_float(__builtin_amdgcn_readlane(eb, 4*q + 1));
                    const float e2 = __uint_as_float(__builtin_amdgcn_readlane(eb, 4*q + 2));
                    const float e3 = __uint_as_float(__builtin_amdgcn_readlane(eb, 4*q + 3));
                    const int v0 = 4*q;
                    const float f0 = (float)*reinterpret_cast<const _Float16*>(
                        (const char*)EH + ((v0 + 0) << 7) + ((lane << 1) ^ (((v0 + 0) & 7) << 4)));
                    const float f1 = (float)*reinterpret_cast<const _Float16*>(
                        (const char*)EH + ((v0 + 1) << 7) + ((lane << 1) ^ (((v0 + 1) & 7) << 4)));
                    const float f2 = (float)*reinterpret_cast<const _Float16*>(
                        (const char*)EH + ((v0 + 2) << 7) + ((lane << 1) ^ (((v0 + 2) & 7) << 4)));
                    const float f3 = (float)*reinterpret_cast<const _Float16*>(
                        (const char*)EH + ((v0 + 3) << 7) + ((lane << 1) ^ (((v0 + 3) & 7) << 4)));
                    a0 = fmaf(e0, f0, a0);
                    a1 = fmaf(e1, f1, a1);
                    a2 = fmaf(e2, f2, a2);
                    a3 = fmaf(e3, f3, a3);
                }
            }
            __syncthreads();   // all waves done reading before next stage
        }
        pooled[(size_t)s * NHID + t] = ((a0 + a1) + (a2 + a3)) / l;
    }
}

// ---------------------------------------------------------------------------
// Kernel D: out = pooled @ W_out
// ---------------------------------------------------------------------------
__global__ __launch_bounds__(256) void out_kernel(
    const float* __restrict__ pooled, const float* __restrict__ Wout,
    float* __restrict__ out)
{
    __shared__ float Pt[16][260];
    const int t = threadIdx.x;
    const int sbase = blockIdx.x << 4;
#pragma unroll
    for (int it = 0; it < 4; ++it) {
        const int idx = t + (it << 8);
        const int row = idx >> 6;
        const int c4 = (idx & 63) << 2;
        *reinterpret_cast<float4*>(&Pt[row][c4]) =
            *reinterpret_cast<const float4*>(pooled + (size_t)(sbase + row) * NHID + c4);
    }
    __syncthreads();
    const int oc = (t & 31) << 2;
    const int sg = t >> 5;
    float a0x = 0.f, a0y = 0.f, a0z = 0.f, a0w = 0.f;
    float a1x = 0.f, a1y = 0.f, a1z = 0.f, a1w = 0.f;
#pragma unroll 4
    for (int k = 0; k < NHID; ++k) {
        const float4 w = *reinterpret_cast<const float4*>(Wout + (size_t)k * NOUT + oc);
        const float p0 = Pt[(sg << 1) + 0][k];
        const float p1 = Pt[(sg << 1) + 1][k];
        a0x = fmaf(p0, w.x, a0x); a0y = fmaf(p0, w.y, a0y);
        a0z = fmaf(p0, w.z, a0z); a0w = fmaf(p0, w.w, a0w);
        a1x = fmaf(p1, w.x, a1x); a1y = fmaf(p1, w.y, a1y);
        a1z = fmaf(p1, w.z, a1z); a1w = fmaf(p1, w.w, a1w);
    }
    *reinterpret_cast<float4*>(out + (size_t)(sbase + (sg << 1) + 0) * NOUT + oc) =
        make_float4(a0x, a0y, a0z, a0w);
    *reinterpret_cast<float4*>(out + (size_t)(sbase + (sg << 1) + 1) * NOUT + oc) =
        make_float4(a1x, a1y, a1z, a1w);
}

// ---------------------------------------------------------------------------
extern "C" void kernel_launch(void* const* d_in, const int* in_sizes, int n_in,
                              void* d_out, int out_size, void* d_ws, size_t ws_size,
                              hipStream_t stream)
{
    const float* emb  = (const float*)d_in[0];
    const float* Wv   = (const float*)d_in[1];
    const float* Wout = (const float*)d_in[2];
    const int*   map  = (const int*)d_in[3];
    float* out = (float*)d_out;

    char* ws = (char*)d_ws;
    float*    pooled = (float*)ws;                    // 10,240,000 B
    int*      start  = (int*)(ws + 10240000);         //     40,004 B
    _Float16* WfH    = (_Float16*)(ws + 10280064);    //     32,768 B
    _Float16* WfL    = (_Float16*)(ws + 10312832);    //     32,768 B

    wconv_kernel<<<8, 256, 0, stream>>>(Wv, WfH, WfL);
    bounds_kernel<<<(NV + 255) / 256, 256, 0, stream>>>(map, start);
    fused_kernel<<<FUSED_GRID, 256, 0, stream>>>(emb, WfH, WfL, start, pooled);
    out_kernel<<<NS / 16, 256, 0, stream>>>(pooled, Wout, out);
}